// Round 7
// baseline (203.769 us; speedup 1.0000x reference)
//
#include <hip/hip_runtime.h>

// Shape fixed by reference: (2,1,160,160,160) fp32, window 11, zero-pad box filter.
// Fields reduced via u=x+y, v=x-y: box{u, v, u^2, v^2} packed in one float4.
// R6: no LDS staging — W-pass reads X,Y straight from global (L1/L2 serve halo
// re-reads); 2 barriers/slab; LDS = wp + Sb only (~11 KB) for max co-residency.
#define DIMX 160
#define DIMY 160
#define DIMZ 160
#define BC   2
#define NTOT (BC * DIMZ * DIMY * DIMX)   // 8,192,000
#define PAD  5
#define TS   16                  // tile size in H and W
#define HS   26                  // TS + 2*PAD rows
#define WPS  17                  // wp row stride in float4 (breaks bank aliasing)
#define CD   20                  // D-chunk per block
#define NCH  (DIMZ / CD)         // 8
#define NTH  (DIMY / TS)         // 10
#define NTW  (DIMX / TS)         // 10
#define NBLK (NCH * BC * NTH * NTW)  // 1600 blocks

static_assert(NTOT == 8192000, "size mismatch");

__device__ __forceinline__ float4 f4add(float4 a, float4 b) {
  return make_float4(a.x + b.x, a.y + b.y, a.z + b.z, a.w + b.w);
}
__device__ __forceinline__ float4 f4sub(float4 a, float4 b) {
  return make_float4(a.x - b.x, a.y - b.y, a.z - b.z, a.w - b.w);
}

// Ring slot update with compile-time index K (keeps ring[] in VGPRs).
#define RING_CASE(K) case K: {                 \
    sums = f4add(sums, f4sub(Sv, ring[K]));    \
    ring[K] = Sv;                              \
  } break;

__device__ __forceinline__ float ssim_term(float4 sm, float inv, float c1, float c2) {
  const float mu_u = sm.x * inv, mu_v = sm.y * inv;
  const float Euu  = sm.z * inv, Evv  = sm.w * inv;
  const float P = mu_u * mu_u, Q = mu_v * mu_v;
  const float sgu = Euu - P, sgv = Evv - Q;
  const float num = (0.5f * (P - Q) + c1) * (0.5f * (sgu - sgv) + c2);
  const float den = (0.5f * (P + Q) + c1) * (0.5f * (sgu + sgv) + c2);
  const float ssim = num * __builtin_amdgcn_rcpf(den + 1e-8f);
  const float val  = 0.5f * (1.f - ssim);
  return fminf(fmaxf(val, 0.f), 1.f);
}

__global__ __launch_bounds__(256) void fused_ssim(const float* __restrict__ X,
                                                  const float* __restrict__ Y,
                                                  float* __restrict__ pssim,
                                                  float* __restrict__ pl1) {
  __shared__ float4 wpf[HS * WPS];   // W-passed {su,sv,suu,svv}: 26*17*16 = 7072 B
  __shared__ float4 Sb[TS * TS];     // H-passed per-voxel fields: 4096 B

  const int tid = threadIdx.x;
  const int bx  = blockIdx.x;
  const int tw  = bx % NTW;
  const int th  = (bx / NTW) % NTH;
  const int b   = (bx / (NTW * NTH)) % BC;
  const int ch  =  bx / (NTW * NTH * BC);
  const int h0 = th * TS, w0 = tw * TS, c0 = ch * CD;
  const size_t bbase = (size_t)b * (DIMZ * DIMY * DIMX);

  // W-pass decomposition (tid < 104): 26 rows x 4 groups of 4 sliding outputs.
  const int wr  = tid >> 2, wg = tid & 3;
  const int wgh = h0 - PAD + wr;                       // global H of this W row
  const bool wrok  = ((unsigned)wgh < (unsigned)DIMY); // row in bounds
  const bool wint  = (wr >= PAD) && (wr < PAD + TS);   // interior row (L1 ownership)
  // H-pass decomposition (tid < 64): 16 cols x 4 quarters of 4 sliding outputs.
  const int qt = tid >> 4, hw = tid & 15;

  float4 ring[11];
#pragma unroll
  for (int k = 0; k < 11; ++k) ring[k] = make_float4(0.f, 0.f, 0.f, 0.f);
  float4 sums = make_float4(0.f, 0.f, 0.f, 0.f);
  float l1loc = 0.f, ssloc = 0.f;

  const float inv = 1.0f / 1331.0f;             // 1/11^3
  const float c1  = 0.01f / (4096.f * 4096.f);  // K1 / data_range^2 (faithful to ref)
  const float c2  = 0.03f / (4096.f * 4096.f);

  int ph = (c0 - PAD + 22) % 11;   // uniform ring phase

  for (int d = c0 - PAD; d < c0 + CD + PAD; ++d) {
    const bool dval = (unsigned)d < (unsigned)DIMZ;
    const bool dIn  = (d >= c0) && (d < c0 + CD);

    // --- W-pass straight from global: 104 threads x 4 sliding outputs ---
    if (dval && tid < 104) {
      float tu[20], tv[20];
      const size_t rb = bbase + (size_t)d * (DIMY * DIMX) + (size_t)wgh * DIMX;
#pragma unroll
      for (int q = 0; q < 5; ++q) {
        const int gc = w0 - 8 + ((wg + q) << 2);   // float4-aligned; 160%4==0 so
        float4 xq = make_float4(0.f, 0.f, 0.f, 0.f), yq = xq;  // never straddles
        if (wrok && (unsigned)gc < (unsigned)DIMX) {
          xq = *(const float4*)(X + rb + gc);
          yq = *(const float4*)(Y + rb + gc);
        }
        tu[4 * q + 0] = xq.x + yq.x;  tv[4 * q + 0] = xq.x - yq.x;
        tu[4 * q + 1] = xq.y + yq.y;  tv[4 * q + 1] = xq.y - yq.y;
        tu[4 * q + 2] = xq.z + yq.z;  tv[4 * q + 2] = xq.z - yq.z;
        tu[4 * q + 3] = xq.w + yq.w;  tv[4 * q + 3] = xq.w - yq.w;
      }
      // smooth-L1 on the 4 owned center voxels (each interior voxel hit once)
      if (dIn && wint) {
#pragma unroll
        for (int k = 0; k < 4; ++k) {
          const float a = fabsf(tv[8 + k]);
          l1loc += (a < 1.f) ? 0.5f * a * a : a - 0.5f;
        }
      }
      // sliding 11-tap sums for u and v
      float su = 0.f, ssu = 0.f, sv = 0.f, ssv = 0.f;
#pragma unroll
      for (int j = 3; j <= 13; ++j) {
        su += tu[j]; ssu = fmaf(tu[j], tu[j], ssu);
        sv += tv[j]; ssv = fmaf(tv[j], tv[j], ssv);
      }
      const int o = wr * WPS + (wg << 2);
      wpf[o] = make_float4(su, sv, ssu, ssv);
#pragma unroll
      for (int k = 1; k < 4; ++k) {
        const float nu = tu[13 + k], ou = tu[2 + k];
        const float nv = tv[13 + k], ov = tv[2 + k];
        su += nu - ou; ssu = fmaf(nu, nu, fmaf(-ou, ou, ssu));
        sv += nv - ov; ssv = fmaf(nv, nv, fmaf(-ov, ov, ssv));
        wpf[o + k] = make_float4(su, sv, ssu, ssv);
      }
    }
    __syncthreads();   // B1: wpf complete (also orders redist(i-1) vs Sb writes below)

    // --- H-pass: 64 threads x 4 sliding outputs (14 b128 reads, 4 writes) ---
    if (dval && tid < 64) {
      const int base = (qt << 2) * WPS + hw;
      const float4 T0 = wpf[base];
      const float4 T1 = wpf[base + WPS];
      const float4 T2 = wpf[base + 2 * WPS];
      float4 S = f4add(f4add(T0, T1), T2);
#pragma unroll
      for (int j = 3; j <= 10; ++j) S = f4add(S, wpf[base + j * WPS]);
      Sb[((qt << 2) + 0) * TS + hw] = S;
      S = f4sub(f4add(S, wpf[base + 11 * WPS]), T0);
      Sb[((qt << 2) + 1) * TS + hw] = S;
      S = f4sub(f4add(S, wpf[base + 12 * WPS]), T1);
      Sb[((qt << 2) + 2) * TS + hw] = S;
      S = f4sub(f4add(S, wpf[base + 13 * WPS]), T2);
      Sb[((qt << 2) + 3) * TS + hw] = S;
    }
    __syncthreads();   // B2: Sb complete; also frees wpf for next iteration's W

    // --- redistribute + D-ring update + SSIM (no trailing barrier needed) ---
    float4 Sv = make_float4(0.f, 0.f, 0.f, 0.f);
    if (dval) Sv = Sb[tid];
    switch (ph) {
      RING_CASE(0) RING_CASE(1) RING_CASE(2) RING_CASE(3) RING_CASE(4)
      RING_CASE(5) RING_CASE(6) RING_CASE(7) RING_CASE(8) RING_CASE(9)
      RING_CASE(10)
    }
    ph = (ph == 10) ? 0 : ph + 1;
    if (d >= c0 + PAD) ssloc += ssim_term(sums, inv, c1, c2);
  }

  // --- block reduction -> per-block partials ---
#pragma unroll
  for (int off = 32; off > 0; off >>= 1) {
    ssloc += __shfl_down(ssloc, off, 64);
    l1loc += __shfl_down(l1loc, off, 64);
  }
  __syncthreads();                 // LDS compute use done; reuse Sb as scratch
  float* scr = (float*)Sb;
  const int lane = tid & 63, wv = tid >> 6;
  if (lane == 0) {
    scr[wv * 2]     = ssloc;
    scr[wv * 2 + 1] = l1loc;
  }
  __syncthreads();
  if (tid == 0) {
    pssim[bx] = scr[0] + scr[2] + scr[4] + scr[6];
    pl1[bx]   = scr[1] + scr[3] + scr[5] + scr[7];
  }
}

// Final: reduce 1600 + 1600 partials in double, emit scalar loss.
__global__ __launch_bounds__(256) void final_reduce(const float* __restrict__ pssim,
                                                    const float* __restrict__ pl1,
                                                    float* __restrict__ out) {
  double s = 0.0, l = 0.0;
  for (int i = threadIdx.x; i < NBLK; i += 256) {
    s += (double)pssim[i];
    l += (double)pl1[i];
  }
#pragma unroll
  for (int off = 32; off > 0; off >>= 1) {
    s += __shfl_down(s, off, 64);
    l += __shfl_down(l, off, 64);
  }
  __shared__ double sm[8];
  const int lane = threadIdx.x & 63, wv = threadIdx.x >> 6;
  if (lane == 0) { sm[wv * 2] = s; sm[wv * 2 + 1] = l; }
  __syncthreads();
  if (threadIdx.x == 0) {
    const double ssm = (sm[0] + sm[2] + sm[4] + sm[6]) / (double)NTOT;
    const double l1m = (sm[1] + sm[3] + sm[5] + sm[7]) / (double)NTOT;
    out[0] = (float)(0.85 * ssm + 0.15 * l1m);
  }
}

extern "C" void kernel_launch(void* const* d_in, const int* in_sizes, int n_in,
                              void* d_out, int out_size, void* d_ws, size_t ws_size,
                              hipStream_t stream) {
  const float* X = (const float*)d_in[0];
  const float* Y = (const float*)d_in[1];
  float* out = (float*)d_out;

  float* pssim = (float*)d_ws;        // NBLK floats
  float* pl1   = pssim + NBLK;        // NBLK floats

  fused_ssim<<<NBLK, 256, 0, stream>>>(X, Y, pssim, pl1);
  final_reduce<<<1, 256, 0, stream>>>(pssim, pl1, out);
}